// Round 5
// baseline (65.588 us; speedup 1.0000x reference)
//
#include <hip/hip_runtime.h>

#define TPB 256
#define RPB 4                         // rows per tile (4-row tiles)
#define SEQ_L 2048
#define NCH 8                         // 256-wide j-chunks
#define NBATCH 8
#define NT4 512                       // 4-row tiles per batch
#define NPAIR 256                     // tile pairs (t, 511-t), t in 0..255
#define NBLOCKS (NBATCH * NPAIR)      // 2048  == 256 CU x 8 blocks/CU
#define NWAVE (TPB / 64)

static constexpr float kBondTol  = 0.4f;
static constexpr float kClashTol = 1.5f;
static constexpr float kIdeal    = 3.8f;
static constexpr float kEps      = 1e-8f;
static constexpr float kThresh2  = 2.25f;   // 1.5^2: d2 >= this -> relu == 0
static constexpr float kFarBase  = 1.0e5f;  // masked-point sentinel base
static constexpr float kHugeD2   = 1.0e12f; // "not a pair" d2 sentinel

__device__ __forceinline__ float wred(float v) {
#pragma unroll
  for (int o = 32; o > 0; o >>= 1) v += __shfl_down(v, o, 64);
  return v;
}

// r4 skeleton (LDS-free, L2-direct, paired 4-row tiles, plain float4 stores,
// separate tiny reduce — NO atomics/fences, r1/r3 proved the ticket chain
// costs ~41us) with the last stragglers/stalls removed:
//  - msq straggler gone: every block stores its local 8-row mask sum to
//    pmsum[]; the reduce kernel rebuilds per-batch msum (deterministic) and
//    adds sum_b msum_b^2. All 2048 blocks now do IDENTICAL work (9 uniform
//    4-row chunk-computes), no pre-sweep barrier anywhere.
//  - depth-3 rolling prefetch: ~2 iters (>=200cy) of slack covers the L2
//    hit latency (~200cy), so the sweep issues back-to-back VALU.
// Masks are geometric sentinels (masked points relocated to spaced far-away
// positions, spacing 4 > 1.5): the hot loop has NO mask weighting. Pair-mask
// denominator is analytic: pm_batch = msum^2 - sum_i mi*nm_i.
__global__ __launch_bounds__(TPB, 8) void viol_main(
    const float* __restrict__ pos,    // [B, L, 3]
    const float* __restrict__ mask,   // [B, L]
    float4* __restrict__ partial,     // [NBLOCKS]: (bv, bm, 2*cv_half, pm)
    float* __restrict__ pmsum) {      // [NBLOCKS]: local 8-row mask sum
  __shared__ float red4[NWAVE][4];

  const int b   = blockIdx.x & 7;     // batch -> XCD-pinned L2 reuse
  const int t   = blockIdx.x >> 3;    // pair index 0..255
  const int i0A = t << 2;             // low 4-row tile
  const int i0B = (NT4 - 1 - t) << 2; // high 4-row tile
  const int k0A = t >> 6;             // 0..3
  const int k0B = (NT4 - 1 - t) >> 6; // 4..7  (k0A + k0B == 7)
  const int tid  = (int)threadIdx.x;
  const int wid  = tid >> 6;
  const int lane = tid & 63;

  const float* pb = pos  + (size_t)b * SEQ_L * 3;
  const float* mb = mask + (size_t)b * SEQ_L;

  // ---- rows (sentineled), wave-uniform loads -> regs ----
  float pxA[RPB], pyA[RPB], pzA[RPB], accA[RPB];
  float pxB[RPB], pyB[RPB], pzB[RPB], accB[RPB];
#pragma unroll
  for (int q = 0; q < RPB; ++q) {
    const int iA = i0A + q, iB = i0B + q;
    float xA = pb[3 * iA], yA = pb[3 * iA + 1], zA = pb[3 * iA + 2];
    float xB = pb[3 * iB], yB = pb[3 * iB + 1], zB = pb[3 * iB + 2];
    if (mb[iA] == 0.f) { xA = kFarBase + 4.f * (float)iA; yA = 0.f; zA = 0.f; }
    if (mb[iB] == 0.f) { xB = kFarBase + 4.f * (float)iB; yB = 0.f; zB = 0.f; }
    pxA[q] = xA; pyA[q] = yA; pzA[q] = zA;
    pxB[q] = xB; pyB[q] = yB; pzB[q] = zB;
    accA[q] = 0.f; accB[q] = 0.f;
  }

  // ---- sweep chunks k0A..7 from L2 with DEPTH-3 rolling prefetch ----
  {
    const int jg0 = tid + (k0A << 8);          // k0A   <= 3
    const int jg1 = jg0 + 256;                 // k0A+1 <= 4
    const int jg2 = jg0 + 512;                 // k0A+2 <= 5  (< NCH always)
    float s0x = pb[3*jg0], s0y = pb[3*jg0+1], s0z = pb[3*jg0+2];
    float s1x = pb[3*jg1], s1y = pb[3*jg1+1], s1z = pb[3*jg1+2];
    float s2x = pb[3*jg2], s2y = pb[3*jg2+1], s2z = pb[3*jg2+2];
    const float m0 = mb[jg0], m1 = mb[jg1], m2 = mb[jg2];
    if (m0 == 0.f) { s0x = kFarBase + 4.f * (float)jg0; s0y = 0.f; s0z = 0.f; }
    if (m1 == 0.f) { s1x = kFarBase + 4.f * (float)jg1; s1y = 0.f; s1z = 0.f; }
    if (m2 == 0.f) { s2x = kFarBase + 4.f * (float)jg2; s2y = 0.f; s2z = 0.f; }

    for (int k = k0A; k < NCH; ++k) {
      const int kn = (k + 3 < NCH) ? k + 3 : NCH - 1;   // dup re-read at end
      const int jn = tid + (kn << 8);
      float nx = pb[3 * jn], ny = pb[3 * jn + 1], nz = pb[3 * jn + 2];
      const float nmm = mb[jn];
      const int j = tid + (k << 8);

      float d2r[RPB];
      // --- tile A (active every iteration; diagonal when k == k0A) ---
#pragma unroll
      for (int q = 0; q < RPB; ++q) {
        const float dx = s0x - pxA[q], dy = s0y - pyA[q], dz = s0z - pzA[q];
        d2r[q] = fmaf(dx, dx, fmaf(dy, dy, dz * dz));
      }
      if (k == k0A) {
#pragma unroll
        for (int q = 0; q < RPB; ++q)
          d2r[q] = (j > i0A + q) ? d2r[q] : kHugeD2;  // strict upper triangle
      }
      {
        const float mv = fminf(fminf(d2r[0], d2r[1]), fminf(d2r[2], d2r[3]));
        if (__ballot(mv < kThresh2) != 0ull) {
#pragma unroll
          for (int q = 0; q < RPB; ++q) {
            const float dist = __builtin_amdgcn_sqrtf(d2r[q] + kEps);
            accA[q] += fmaxf(kClashTol - dist, 0.f);
          }
        }
      }
      // --- tile B (active for k >= k0B; diagonal when k == k0B) ---
      if (k >= k0B) {
#pragma unroll
        for (int q = 0; q < RPB; ++q) {
          const float dx = s0x - pxB[q], dy = s0y - pyB[q], dz = s0z - pzB[q];
          d2r[q] = fmaf(dx, dx, fmaf(dy, dy, dz * dz));
        }
        if (k == k0B) {
#pragma unroll
          for (int q = 0; q < RPB; ++q)
            d2r[q] = (j > i0B + q) ? d2r[q] : kHugeD2;
        }
        const float mv = fminf(fminf(d2r[0], d2r[1]), fminf(d2r[2], d2r[3]));
        if (__ballot(mv < kThresh2) != 0ull) {
#pragma unroll
          for (int q = 0; q < RPB; ++q) {
            const float dist = __builtin_amdgcn_sqrtf(d2r[q] + kEps);
            accB[q] += fmaxf(kClashTol - dist, 0.f);
          }
        }
      }
      // rotate prefetch pipeline (apply sentinel to the new arrival)
      if (nmm == 0.f) { nx = kFarBase + 4.f * (float)jn; ny = 0.f; nz = 0.f; }
      s0x = s1x; s0y = s1y; s0z = s1z;
      s1x = s2x; s1y = s2y; s1z = s2z;
      s2x = nx;  s2y = ny;  s2z = nz;
    }
  }

  float cv = 0.f;
#pragma unroll
  for (int q = 0; q < RPB; ++q) cv += accA[q] + accB[q];

  // ---- tail (8 rows): near-diag cancel + bond + pm stencil + local msum ----
  float bv = 0.f, bm = 0.f, pm = 0.f, lm = 0.f;
  if (tid < 8) {
    const int i = (tid < 4) ? (i0A + tid) : (i0B + (tid - 4));
    const float mi = mb[i];
    lm = mi;                          // block-local mask sum contribution
    const float xi = pb[3 * i], yi = pb[3 * i + 1], zi = pb[3 * i + 2];
    float sxi = xi, syi = yi, szi = zi;                 // sentineled copy
    if (mi == 0.f) { sxi = kFarBase + 4.f * (float)i; syi = 0.f; szi = 0.f; }
    const int jhi = (i + 2 > SEQ_L - 1) ? SEQ_L - 1 : i + 2;

    float nv = 0.f;                   // cancel exactly what the sweep added
    for (int jj = i + 1; jj <= jhi; ++jj) {
      float xj = pb[3 * jj], yj = pb[3 * jj + 1], zj = pb[3 * jj + 2];
      if (mb[jj] == 0.f) { xj = kFarBase + 4.f * (float)jj; yj = 0.f; zj = 0.f; }
      const float dx = xj - sxi, dy = yj - syi, dz = zj - szi;
      const float dist = __builtin_amdgcn_sqrtf(dx*dx + dy*dy + dz*dz + kEps);
      nv += fmaxf(kClashTol - dist, 0.f);
    }
    cv -= nv;

    float nm_ = 0.f;                  // real masks, |i-j|<=2 incl. j==i
    const int jlo = (i - 2 < 0) ? 0 : i - 2;
    for (int jj = jlo; jj <= jhi; ++jj) nm_ += mb[jj];
    pm = -mi * nm_;                   // msum^2 reconstructed in reduce

    if (i < SEQ_L - 1) {              // bond term: RAW positions, mask product
      const float dx = pb[3*(i+1)]   - xi;
      const float dy = pb[3*(i+1)+1] - yi;
      const float dz = pb[3*(i+1)+2] - zi;
      const float dist = __builtin_amdgcn_sqrtf(dx*dx + dy*dy + dz*dz + kEps);
      const float mj = mb[i + 1];
      bv = fmaxf(fabsf(dist - kIdeal) - kBondTol, 0.f) * mi * mj;
      bm = mi * mj;
    }
  }

  // local mask sum lives in wave 0 only; store before the cross-wave reduce
  lm = wred(lm);
  if (tid == 0) pmsum[blockIdx.x] = lm;

  // ---- block reduction -> ONE plain float4 store (no atomics, no fences) ----
  bv = wred(bv); bm = wred(bm); cv = wred(cv); pm = wred(pm);
  if (lane == 0) {
    red4[wid][0] = bv; red4[wid][1] = bm;
    red4[wid][2] = cv; red4[wid][3] = pm;
  }
  __syncthreads();
  if (tid == 0) {
    float tbv = 0.f, tbm = 0.f, tcv = 0.f, tpm = 0.f;
#pragma unroll
    for (int w = 0; w < NWAVE; ++w) {
      tbv += red4[w][0]; tbm += red4[w][1];
      tcv += red4[w][2]; tpm += red4[w][3];
    }
    // x2: upper triangle -> full ordered sum
    partial[blockIdx.x] = make_float4(tbv, tbm, 2.f * tcv, tpm);
  }
}

__global__ __launch_bounds__(TPB) void viol_reduce(
    const float4* __restrict__ partial,
    const float* __restrict__ pmsum,
    float* __restrict__ out) {
  __shared__ float red4[NWAVE][4];
  __shared__ float sms[TPB];
  __shared__ float ssq[8];
  float bv = 0.f, bm = 0.f, cv = 0.f, pm = 0.f, ms = 0.f;
  // stride TPB=256 is a multiple of 8, so each thread only ever touches
  // partials of batch (tid & 7): per-thread ms is single-batch by design.
#pragma unroll
  for (int i = threadIdx.x; i < NBLOCKS; i += TPB) {
    float4 p = partial[i];
    bv += p.x; bm += p.y; cv += p.z; pm += p.w;
    ms += pmsum[i];
  }
  sms[threadIdx.x] = ms;
  bv = wred(bv); bm = wred(bm); cv = wred(cv); pm = wred(pm);
  const int wid  = threadIdx.x >> 6;
  const int lane = threadIdx.x & 63;
  if (lane == 0) {
    red4[wid][0] = bv; red4[wid][1] = bm;
    red4[wid][2] = cv; red4[wid][3] = pm;
  }
  __syncthreads();
  if (threadIdx.x < 8) {              // per-batch msum, fixed order
    float msb = 0.f;
#pragma unroll
    for (int g = 0; g < TPB / 8; ++g) msb += sms[threadIdx.x + 8 * g];
    ssq[threadIdx.x] = msb * msb;
  }
  __syncthreads();
  if (threadIdx.x == 0) {
    float tbv = 0.f, tbm = 0.f, tcv = 0.f, tpm = 0.f;
#pragma unroll
    for (int w = 0; w < NWAVE; ++w) {
      tbv += red4[w][0]; tbm += red4[w][1];
      tcv += red4[w][2]; tpm += red4[w][3];
    }
#pragma unroll
    for (int b = 0; b < 8; ++b) tpm += ssq[b];   // + sum_b msum_b^2
    float bond  = tbv / (tbm + kEps);
    float clash = tcv / (tpm + kEps);
    out[0] = bond;
    out[1] = clash;
    out[2] = bond + clash;
  }
}

extern "C" void kernel_launch(void* const* d_in, const int* in_sizes, int n_in,
                              void* d_out, int out_size, void* d_ws, size_t ws_size,
                              hipStream_t stream) {
  const float* pos  = (const float*)d_in[0];
  const float* mask = (const float*)d_in[1];
  float* out = (float*)d_out;
  float4* partial = (float4*)d_ws;                          // 32 KB
  float*  pmsum   = (float*)((char*)d_ws + NBLOCKS * sizeof(float4)); // 8 KB

  viol_main<<<dim3(NBLOCKS), dim3(TPB), 0, stream>>>(pos, mask, partial, pmsum);
  viol_reduce<<<dim3(1), dim3(TPB), 0, stream>>>(partial, pmsum, out);
}